// Round 1
// baseline (342.205 us; speedup 1.0000x reference)
//
#include <hip/hip_runtime.h>
#include <hip/hip_bf16.h>
#include <math.h>

#define B_ 64
#define T_ 512
#define D_ 1024
#define M_ (B_*T_)   // 32768 rows of x flattened [B*T, D]

typedef unsigned short u16;
typedef __attribute__((ext_vector_type(8))) _Float16 f16x8;  // 8 fp16 in 4 VGPRs
typedef __attribute__((ext_vector_type(4))) float f32x4;

// fp32 -> fp16 RNE, bit pattern
__device__ __forceinline__ u16 f2h(float f) {
  union { _Float16 h; u16 u; } v;
  v.h = (_Float16)f;
  return v.u;
}

__device__ __forceinline__ float h2f(u16 u) {
  union { u16 u; _Float16 h; } v;
  v.u = u;
  return (float)v.h;
}

__device__ __forceinline__ float fast_tanh(float x) {
  // tanh(x) = 1 - 2/(exp(2x)+1); saturates correctly at +/-inf of expf
  return 1.0f - 2.0f / (__expf(2.0f * x) + 1.0f);
}

// async global->LDS, 16B per lane; LDS dest = wave-uniform base + lane*16
__device__ __forceinline__ void gll16(const void* g, void* l) {
  __builtin_amdgcn_global_load_lds(
      (const __attribute__((address_space(1))) unsigned int*)g,
      (__attribute__((address_space(3))) unsigned int*)l, 16, 0, 0);
}

// ---------------- K0: fused cvt — blocks <32768: x fp32->fp16; rest: W -> Wt ------
__global__ __launch_bounds__(256) void cvt_kernel(const float4* __restrict__ x,
                                                  ushort4* __restrict__ xh,
                                                  const float* __restrict__ W,
                                                  u16* __restrict__ wt) {
  __shared__ float tile[32][33];
  const int bid = blockIdx.x;
  if (bid < 32768) {
    int i = bid * 256 + threadIdx.x;
    float4 v = x[i];
    ushort4 o;
    o.x = f2h(v.x); o.y = f2h(v.y); o.z = f2h(v.z); o.w = f2h(v.w);
    xh[i] = o;
  } else {
    const int tb = bid - 32768;                 // 1024 transpose tiles
    const int n0 = (tb & 31) * 32, k0 = (tb >> 5) * 32;
    const int tx = threadIdx.x & 31, ty = threadIdx.x >> 5;  // ty 0..7
#pragma unroll
    for (int ph = 0; ph < 4; ph++)
      tile[ty + ph * 8][tx] = W[(k0 + ty + ph * 8) * D_ + n0 + tx];
    __syncthreads();
#pragma unroll
    for (int ph = 0; ph < 4; ph++)
      wt[(long)(n0 + ty + ph * 8) * D_ + k0 + tx] = f2h(tile[tx][ty + ph * 8]);
  }
}

// ---------------- shared 256x256 core: BK=32, 8 waves, ring-4 LDS, counted vmcnt ----
// Swizzle identical to the verified BK=32 core128: chunk c of within-group row r
// stored at position (c + (r>>1)) & 3; measured 0 bank conflicts.
// Ring-4 pipeline: iteration t consumes buf[t&3]; loads for tile t+3 are issued
// AFTER iteration t's barrier into buf[(t+3)&3] == buf[(t-1)&3] (dead: its last
// ds_read was lgkm-consumed before that same barrier). R-A-W: each wave executes
// s_waitcnt vmcnt(8) before the barrier (12 outstanding - 8 = the 4 oldest =
// tile t's loads). vmcnt never drains to 0 in the main loop (T4); epilogue peels
// vmcnt(4)/vmcnt(0). s_setprio(1) around the MFMA cluster (T5).
struct Stage {
  const u16* gA[2]; const u16* gB[2];
  u16* lA[2]; u16* lB[2];
  int t;
  __device__ __forceinline__ void issue() {
    const int sb = (t & 3) * 8192;             // buf offset in u16 (16 KB)
#pragma unroll
    for (int j = 0; j < 2; j++) {
      gll16(gA[j], lA[j] + sb);
      gll16(gB[j], lB[j] + sb);
      gA[j] += 32; gB[j] += 32;                // next BK=32 chunk along K
    }
    t++;
  }
};

template<int VMN>
__device__ __forceinline__ void core_step(Stage& st, bool do_issue,
                                          const u16* ra, const u16* rb, int buf,
                                          f32x4 (&acc)[8][4]) {
  if constexpr (VMN == 8)      asm volatile("s_waitcnt vmcnt(8)" ::: "memory");
  else if constexpr (VMN == 4) asm volatile("s_waitcnt vmcnt(4)" ::: "memory");
  else                         asm volatile("s_waitcnt vmcnt(0)" ::: "memory");
  __builtin_amdgcn_s_barrier();
  asm volatile("" ::: "memory");               // no LDS-read motion across barrier
  __builtin_amdgcn_sched_barrier(0);
  if (do_issue) st.issue();                    // tile t+3 -> dead ring slot
  const u16* rat = ra + buf * 8192;
  const u16* rbt = rb + buf * 8192;
  f16x8 af[8], bfr[4];
#pragma unroll
  for (int i = 0; i < 8; i++) af[i] = *(const f16x8*)(rat + i * 512);
#pragma unroll
  for (int i = 0; i < 4; i++) bfr[i] = *(const f16x8*)(rbt + i * 512);
  __builtin_amdgcn_s_setprio(1);
#pragma unroll
  for (int mi = 0; mi < 8; mi++)
#pragma unroll
    for (int ni = 0; ni < 4; ni++)
      acc[mi][ni] = __builtin_amdgcn_mfma_f32_16x16x32_f16(af[mi], bfr[ni], acc[mi][ni], 0, 0, 0);
  __builtin_amdgcn_s_setprio(0);
}

// A,B row-major [rows x 1024], K contiguous. Tile 256x256, wave tile 128x64.
__device__ __forceinline__ void gemm_core256(const u16* __restrict__ Abase,
                                             const u16* __restrict__ Bbase,
                                             u16* As, u16* Bs, int tid,
                                             f32x4 (&acc)[8][4]) {
  const int wave = tid >> 6, lane = tid & 63;
  const int swz_c = ((lane & 3) - ((lane >> 3) & 3)) & 3;
  const int rin = lane >> 2;                   // within-group row 0..15
  Stage st; st.t = 0;
#pragma unroll
  for (int j = 0; j < 2; j++) {                // 16 row-groups each for A and B
    const int ci = wave * 2 + j;
    st.gA[j] = Abase + (long)(ci * 16 + rin) * D_ + swz_c * 8;
    st.lA[j] = As + ci * 512;
    st.gB[j] = Bbase + (long)(ci * 16 + rin) * D_ + swz_c * 8;
    st.lB[j] = Bs + ci * 512;
  }
  st.issue(); st.issue(); st.issue();          // prologue: tiles 0,1,2 in flight
  const int wrow = (wave >> 2) * 128, wcol = (wave & 3) * 64;
  const int lm = lane & 15, qd = lane >> 4;
  const int swz_r = ((qd + (lm >> 1)) & 3) * 8;
  const u16* ra = As + (wrow + lm) * 32 + swz_r;
  const u16* rb = Bs + (wcol + lm) * 32 + swz_r;
#pragma unroll 1
  for (int t = 0; t < 30; t++)
    core_step<8>(st, t < 29, ra, rb, t & 3, acc);   // last issue at t=28 (tile 31)
  core_step<4>(st, false, ra, rb, 30 & 3, acc);
  core_step<0>(st, false, ra, rb, 31 & 3, acc);
}

// ---------------- K1: xw = x @ W — 256x256 tile, 512 blocks, 8 waves ----------------
__global__ __launch_bounds__(512, 2) void gemm1_kernel(const u16* __restrict__ xh,
                                                       const u16* __restrict__ wt,
                                                       u16* __restrict__ xw) {
  __shared__ u16 As[4 * 8192];   // 64 KB: ring of 4 x (256x32) fp16
  __shared__ u16 Bs[4 * 8192];   // 64 KB
  f32x4 acc[8][4] = {};
  const int tid = threadIdx.x;
  const int bx = blockIdx.x;                 // 512 blocks
  const int xcd = bx & 7, j = bx >> 3;       // j in [0,64)
  const int mt = xcd * 16 + (j >> 2);        // 128 m-tiles of 256 rows
  const int nt = j & 3;                      // 4 n-tiles of 256
  const long m0 = (long)mt * 256, n0 = (long)nt * 256;
  gemm_core256(xh + m0 * D_, wt + n0 * D_, As, Bs, tid, acc);

  const int wave = tid >> 6, lane = tid & 63;
  const int wrow = (wave >> 2) * 128, wcol = (wave & 3) * 64;
  const int lm = lane & 15, qd = lane >> 4;
#pragma unroll
  for (int mi = 0; mi < 8; mi++)
#pragma unroll
    for (int ni = 0; ni < 4; ni++) {
      long m = m0 + wrow + mi * 16 + qd * 4;   // C/D: row=(lane>>4)*4+reg
      long n = n0 + wcol + ni * 16 + lm;       //      col=lane&15
      u16* ptr = xw + m * D_ + n;
#pragma unroll
      for (int r = 0; r < 4; r++) ptr[(long)r * D_] = f2h(acc[mi][ni][r]);
    }
}

// ---------------- K2: eij 256x256 tile + fused tanh*cv reduction -> partial scores ----
// 256 blocks (1/CU). 4 blocks per batch share xw/xh panels in XCD-L2.
// 8 planes: plane = st*4 + (wave&3); each plane covers a disjoint 64-wide s-range.
__global__ __launch_bounds__(512, 2) void gemm2_kernel(const u16* __restrict__ xw,
                                                       const u16* __restrict__ xh,
                                                       const float* __restrict__ bias,
                                                       const float* __restrict__ cv,
                                                       float* __restrict__ scores_part) {
  __shared__ u16 As[4 * 8192];
  __shared__ u16 Bs[4 * 8192];
  f32x4 acc[8][4] = {};
  const int tid = threadIdx.x;
  const int bx = blockIdx.x;                 // 256 blocks
  const int xcd = bx & 7, j = bx >> 3;       // j in [0,32)
  const int bb = xcd * 8 + (j >> 2);         // 64 batches, 8 per XCD
  const int tile = j & 3;
  const int tt = tile >> 1, st_ = tile & 1;  // t-half, s-half
  const long arow = (long)bb * T_ + tt * 256;
  const long brow = (long)bb * T_ + st_ * 256;
  gemm_core256(xw + arow * D_, xh + brow * D_, As, Bs, tid, acc);

  const int wave = tid >> 6, lane = tid & 63;
  const int wrow = (wave >> 2) * 128, wcol = (wave & 3) * 64;
  const int lm = lane & 15, qd = lane >> 4;
  float cvv[4], bv[4];
#pragma unroll
  for (int ni = 0; ni < 4; ni++) {
    int s = st_ * 256 + wcol + ni * 16 + lm;
    cvv[ni] = cv[s];
    bv[ni] = bias[s];
  }
  const int plane = st_ * 4 + (wave & 3);
  float* dst = scores_part + plane * (B_ * T_) + bb * T_ + tt * 256;
#pragma unroll
  for (int mi = 0; mi < 8; mi++) {
#pragma unroll
    for (int r = 0; r < 4; r++) {
      float p = 0.f;
#pragma unroll
      for (int ni = 0; ni < 4; ni++) p += fast_tanh(acc[mi][ni][r] + bv[ni]) * cvv[ni];
      p += __shfl_xor(p, 1); p += __shfl_xor(p, 2);
      p += __shfl_xor(p, 4); p += __shfl_xor(p, 8);
      if (lm == 0) dst[wrow + mi * 16 + qd * 4 + r] = p;   // unique (plane,b,t) owner
    }
  }
}

// ---------------- K3: fused masked-softmax + weighted-sum ----------------
// grid (64,4) x 256 thr. Each block: softmax of batch b (redundant x4, cheap),
// a_out written by dq==0 blocks only; then wsum of its 256-d slice (atomic-free).
__global__ __launch_bounds__(256) void sm_wsum_kernel(const float* __restrict__ sp,
                                                      const unsigned char* __restrict__ m8,
                                                      const u16* __restrict__ xh,
                                                      float* __restrict__ a_out,
                                                      float* __restrict__ out) {
  __shared__ float a_sh[512];
  __shared__ float red[8];
  __shared__ int nonz;
  __shared__ float4 lred[4][64];
  const int b = blockIdx.x, dq = blockIdx.y, tid = threadIdx.x;
  const int w = tid >> 6, ln = tid & 63;
  if (tid == 0) nonz = 0;
  __syncthreads();
  // detect int32-vs-uint8 bool storage from first 512 mask words
  {
    unsigned char c = m8[tid * 4 + 1] | m8[tid * 4 + 2] | m8[tid * 4 + 3] |
                      m8[(tid + 256) * 4 + 1] | m8[(tid + 256) * 4 + 2] | m8[(tid + 256) * 4 + 3];
    if (c) atomicOr(&nonz, 1);
  }
  __syncthreads();
  const bool is_i32 = (nonz == 0);
  float v[2]; bool valid[2];
#pragma unroll
  for (int h = 0; h < 2; h++) {
    int t = tid + h * 256;
    int idx = b * T_ + t;
    valid[h] = is_i32 ? (m8[(long)idx * 4] != 0) : (m8[idx] != 0);
    float s = 0.f;
#pragma unroll
    for (int pl = 0; pl < 8; pl++) s += sp[pl * (B_ * T_) + idx];
    v[h] = valid[h] ? s : -INFINITY;
  }
  float m = fmaxf(v[0], v[1]);
#pragma unroll
  for (int o = 32; o > 0; o >>= 1) m = fmaxf(m, __shfl_xor(m, o));
  if (ln == 0) red[w] = m;
  __syncthreads();
  const float rowmax = fmaxf(fmaxf(red[0], red[1]), fmaxf(red[2], red[3]));
  float e0 = valid[0] ? expf(v[0] - rowmax) : 0.f;
  float e1 = valid[1] ? expf(v[1] - rowmax) : 0.f;
  float ss = e0 + e1;
#pragma unroll
  for (int o = 32; o > 0; o >>= 1) ss += __shfl_xor(ss, o);
  if (ln == 0) red[4 + w] = ss;
  __syncthreads();
  const float tot = red[4] + red[5] + red[6] + red[7];
  const float a0 = e0 / tot, a1 = e1 / tot;
  a_sh[tid] = a0; a_sh[tid + 256] = a1;
  if (dq == 0) {
    a_out[b * T_ + tid] = a0;
    a_out[b * T_ + tid + 256] = a1;
  }
  __syncthreads();
  // weighted sum: lane covers 4 d's; wave w sums t in [w*128,(w+1)*128)
  const int d0 = dq * 256 + ln * 4;
  const u16* xp = xh + (long)b * T_ * D_ + d0;
  float4 acc = make_float4(0.f, 0.f, 0.f, 0.f);
  for (int i = 0; i < 128; i++) {
    int t = w * 128 + i;
    float av = a_sh[t];
    ushort4 xv = *(const ushort4*)(xp + (long)t * D_);
    acc.x += av * h2f(xv.x); acc.y += av * h2f(xv.y);
    acc.z += av * h2f(xv.z); acc.w += av * h2f(xv.w);
  }
  lred[w][ln] = acc;
  __syncthreads();
  if (w == 0) {
    float4 s0 = lred[0][ln], s1 = lred[1][ln], s2 = lred[2][ln], s3 = lred[3][ln];
    float4 s;
    s.x = s0.x + s1.x + s2.x + s3.x;
    s.y = s0.y + s1.y + s2.y + s3.y;
    s.z = s0.z + s1.z + s2.z + s3.z;
    s.w = s0.w + s1.w + s2.w + s3.w;
    *(float4*)(out + (long)b * D_ + d0) = s;
  }
}

extern "C" void kernel_launch(void* const* d_in, const int* in_sizes, int n_in,
                              void* d_out, int out_size, void* d_ws, size_t ws_size,
                              hipStream_t stream) {
  const float* x = (const float*)d_in[0];
  const unsigned char* mask = (const unsigned char*)d_in[1];
  const float* W = (const float*)d_in[2];
  const float* cv = (const float*)d_in[3];
  const float* bias = (const float*)d_in[4];

  float* out = (float*)d_out;                  // [B,D]
  float* a_out = out + (size_t)B_ * D_;        // [B,T]

  // workspace layout (130 MiB): scores_part (1 MiB, 8 planes) aliases wt (dead after gemm1)
  char* ws = (char*)d_ws;
  u16* xh = (u16*)(ws);                         // fp16 x    [M_, D_]  64 MiB
  u16* wt = (u16*)(ws + 67108864);              // fp16 W^T  [D_, D_]   2 MiB
  float* scores_part = (float*)(ws + 67108864); // fp32 [8][B_,T_] 1 MiB (aliases wt)
  u16* xw = (u16*)(ws + 69206016);              // fp16 x@W  [M_, D_]  64 MiB

  cvt_kernel<<<32768 + 1024, 256, 0, stream>>>((const float4*)x, (ushort4*)xh, W, wt);
  gemm1_kernel<<<512, 512, 0, stream>>>(xh, wt, xw);
  gemm2_kernel<<<256, 512, 0, stream>>>(xw, xh, bias, cv, scores_part);
  sm_wsum_kernel<<<dim3(B_, 4), 256, 0, stream>>>(scores_part, mask, xh, a_out, out);
}

// Round 2
// 327.281 us; speedup vs baseline: 1.0456x; 1.0456x over previous
//
#include <hip/hip_runtime.h>
#include <hip/hip_bf16.h>
#include <math.h>

#define B_ 64
#define T_ 512
#define D_ 1024
#define M_ (B_*T_)   // 32768 rows of x flattened [B*T, D]

typedef unsigned short u16;
typedef __attribute__((ext_vector_type(8))) _Float16 f16x8;  // 8 fp16 in 4 VGPRs
typedef __attribute__((ext_vector_type(4))) float f32x4;

// fp32 -> fp16 RNE, bit pattern
__device__ __forceinline__ u16 f2h(float f) {
  union { _Float16 h; u16 u; } v;
  v.h = (_Float16)f;
  return v.u;
}

__device__ __forceinline__ float h2f(u16 u) {
  union { u16 u; _Float16 h; } v;
  v.u = u;
  return (float)v.h;
}

__device__ __forceinline__ float fast_tanh(float x) {
  // tanh(x) = 1 - 2/(exp(2x)+1); saturates correctly at +/-inf of expf
  return 1.0f - 2.0f / (__expf(2.0f * x) + 1.0f);
}

// async global->LDS, 16B per lane; LDS dest = wave-uniform base + lane*16
__device__ __forceinline__ void gll16(const void* g, void* l) {
  __builtin_amdgcn_global_load_lds(
      (const __attribute__((address_space(1))) unsigned int*)g,
      (__attribute__((address_space(3))) unsigned int*)l, 16, 0, 0);
}

// ---------------- K0: fused cvt — blocks <32768: x fp32->fp16; rest: W -> Wt ------
__global__ __launch_bounds__(256) void cvt_kernel(const float4* __restrict__ x,
                                                  ushort4* __restrict__ xh,
                                                  const float* __restrict__ W,
                                                  u16* __restrict__ wt) {
  __shared__ float tile[32][33];
  const int bid = blockIdx.x;
  if (bid < 32768) {
    int i = bid * 256 + threadIdx.x;
    float4 v = x[i];
    ushort4 o;
    o.x = f2h(v.x); o.y = f2h(v.y); o.z = f2h(v.z); o.w = f2h(v.w);
    xh[i] = o;
  } else {
    const int tb = bid - 32768;                 // 1024 transpose tiles
    const int n0 = (tb & 31) * 32, k0 = (tb >> 5) * 32;
    const int tx = threadIdx.x & 31, ty = threadIdx.x >> 5;  // ty 0..7
#pragma unroll
    for (int ph = 0; ph < 4; ph++)
      tile[ty + ph * 8][tx] = W[(k0 + ty + ph * 8) * D_ + n0 + tx];
    __syncthreads();
#pragma unroll
    for (int ph = 0; ph < 4; ph++)
      wt[(long)(n0 + ty + ph * 8) * D_ + k0 + tx] = f2h(tile[tx][ty + ph * 8]);
  }
}

// ---------------- shared 256x256 core: BK=32, 8 waves, ring-4 LDS, 8-phase-style ----
// Data layout IDENTICAL to the verified round-1 kernel (PASSED, 0 bank conflicts):
//   staging swizzle: chunk c of within-group row r at position (c + (r>>1)) & 3
//   slot s of ring-4 at offset s*8192 u16 (A and B each 16 KB/slot).
// Schedule = m201 template cadence: per BK=32 step, TWO phases, each
//   { ds_read subtile ; 2 x global_load_lds ; s_barrier ; lgkmcnt(0) ;
//     setprio(1) ; 16 MFMA ; setprio(0) ; s_barrier }
// Counted vmcnt(8) once per step, placed before phase-1's first barrier: it
// gates slot t+1 (12 outstanding - 8 = the 4 oldest). After that barrier ALL
// waves' slot-(t+1) loads have landed -> step t+1 may ds_read immediately.
// Restage of slot s (at step s+... = issue for tile t+3 into slot (t-1)&3)
// happens one full barrier after the last read of that slot. vmcnt never 0 in
// the main loop; epilogue peels 8 -> 4 -> 0.
struct Stage {
  const u16* gA[2]; const u16* gB[2];
  u16* lA[2]; u16* lB[2];
  int t;
  __device__ __forceinline__ void issueA() {
    const int sb = (t & 3) * 8192;
    gll16(gA[0], lA[0] + sb); gA[0] += 32;
    gll16(gA[1], lA[1] + sb); gA[1] += 32;
  }
  __device__ __forceinline__ void issueB() {
    const int sb = (t & 3) * 8192;
    gll16(gB[0], lB[0] + sb); gB[0] += 32;
    gll16(gB[1], lB[1] + sb); gB[1] += 32;
    t++;
  }
};

__device__ __forceinline__ void mfma_acc(f32x4& a, f16x8 x, f16x8 y) {
  a = __builtin_amdgcn_mfma_f32_16x16x32_f16(x, y, a, 0, 0, 0);
}

template<int SLOT, int VMN, bool ISSUE>
__device__ __forceinline__ void step256(Stage& st, const u16* ra, const u16* rb,
                                        f32x4 (&acc)[8][4]) {
  const u16* rat = ra + SLOT * 8192;
  const u16* rbt = rb + SLOT * 8192;
  f16x8 af[8], bf0, bf1;
  // ---------- phase 0: ds_read A(8)+B(2), stage A-half, MFMA ni=0,1 ----------
#pragma unroll
  for (int i = 0; i < 8; i++) af[i] = *(const f16x8*)(rat + i * 512);
  bf0 = *(const f16x8*)(rbt);
  bf1 = *(const f16x8*)(rbt + 512);
  if (ISSUE) st.issueA();
  __builtin_amdgcn_s_barrier();
  asm volatile("s_waitcnt lgkmcnt(0)" ::: "memory");
  __builtin_amdgcn_sched_barrier(0);
  __builtin_amdgcn_s_setprio(1);
#pragma unroll
  for (int mi = 0; mi < 8; mi++) {
    mfma_acc(acc[mi][0], af[mi], bf0);
    mfma_acc(acc[mi][1], af[mi], bf1);
  }
  __builtin_amdgcn_s_setprio(0);
  __builtin_amdgcn_s_barrier();
  // ---------- phase 1: ds_read B(2), stage B-half, vmcnt gate, MFMA ni=2,3 ----------
  f16x8 bf2 = *(const f16x8*)(rbt + 2 * 512);
  f16x8 bf3 = *(const f16x8*)(rbt + 3 * 512);
  if (ISSUE) st.issueB();
  if constexpr (VMN == 8)      asm volatile("s_waitcnt vmcnt(8)" ::: "memory");
  else if constexpr (VMN == 4) asm volatile("s_waitcnt vmcnt(4)" ::: "memory");
  else if constexpr (VMN == 0) asm volatile("s_waitcnt vmcnt(0)" ::: "memory");
  __builtin_amdgcn_s_barrier();
  asm volatile("s_waitcnt lgkmcnt(0)" ::: "memory");
  __builtin_amdgcn_sched_barrier(0);
  __builtin_amdgcn_s_setprio(1);
#pragma unroll
  for (int mi = 0; mi < 8; mi++) {
    mfma_acc(acc[mi][2], af[mi], bf2);
    mfma_acc(acc[mi][3], af[mi], bf3);
  }
  __builtin_amdgcn_s_setprio(0);
  __builtin_amdgcn_s_barrier();
}

// A,B row-major [rows x 1024], K contiguous. Tile 256x256, wave tile 128x64.
__device__ __forceinline__ void gemm_core256(const u16* __restrict__ Abase,
                                             const u16* __restrict__ Bbase,
                                             u16* As, u16* Bs, int tid,
                                             f32x4 (&acc)[8][4]) {
  const int wave = tid >> 6, lane = tid & 63;
  const int swz_c = ((lane & 3) - ((lane >> 3) & 3)) & 3;
  const int rin = lane >> 2;                   // within-group row 0..15
  Stage st; st.t = 0;
#pragma unroll
  for (int j = 0; j < 2; j++) {                // 16 row-groups each for A and B
    const int ci = wave * 2 + j;
    st.gA[j] = Abase + (long)(ci * 16 + rin) * D_ + swz_c * 8;
    st.lA[j] = As + ci * 512;
    st.gB[j] = Bbase + (long)(ci * 16 + rin) * D_ + swz_c * 8;
    st.lB[j] = Bs + ci * 512;
  }
  // prologue: slots 0,1,2 in flight (12 loads); gate slot 0, sync all waves
  st.issueA(); st.issueB();
  st.issueA(); st.issueB();
  st.issueA(); st.issueB();
  asm volatile("s_waitcnt vmcnt(8)" ::: "memory");
  __builtin_amdgcn_s_barrier();

  const int wrow = (wave >> 2) * 128, wcol = (wave & 3) * 64;
  const int lm = lane & 15, qd = lane >> 4;
  const int swz_r = ((qd + (lm >> 1)) & 3) * 8;
  const u16* ra = As + (wrow + lm) * 32 + swz_r;
  const u16* rb = Bs + (wcol + lm) * 32 + swz_r;

#pragma unroll 1
  for (int it = 0; it < 7; ++it) {             // steps 0..27
    step256<0, 8, true>(st, ra, rb, acc);
    step256<1, 8, true>(st, ra, rb, acc);
    step256<2, 8, true>(st, ra, rb, acc);
    step256<3, 8, true>(st, ra, rb, acc);
  }
  step256<0, 8, true >(st, ra, rb, acc);       // t=28 (stages slot for tile 31)
  step256<1, 4, false>(st, ra, rb, acc);       // t=29
  step256<2, 0, false>(st, ra, rb, acc);       // t=30
  step256<3, -1, false>(st, ra, rb, acc);      // t=31
}

// ---------------- K1: xw = x @ W — 256x256 tile, 512 blocks, 8 waves ----------------
__global__ __launch_bounds__(512, 2) void gemm1_kernel(const u16* __restrict__ xh,
                                                       const u16* __restrict__ wt,
                                                       u16* __restrict__ xw) {
  __shared__ u16 As[4 * 8192];   // 64 KB: ring of 4 x (256x32) fp16
  __shared__ u16 Bs[4 * 8192];   // 64 KB
  f32x4 acc[8][4] = {};
  const int tid = threadIdx.x;
  const int bx = blockIdx.x;                 // 512 blocks
  const int xcd = bx & 7, j = bx >> 3;       // j in [0,64)
  const int mt = xcd * 16 + (j >> 2);        // 128 m-tiles of 256 rows
  const int nt = j & 3;                      // 4 n-tiles of 256
  const long m0 = (long)mt * 256, n0 = (long)nt * 256;
  gemm_core256(xh + m0 * D_, wt + n0 * D_, As, Bs, tid, acc);

  const int wave = tid >> 6, lane = tid & 63;
  const int wrow = (wave >> 2) * 128, wcol = (wave & 3) * 64;
  const int lm = lane & 15, qd = lane >> 4;
#pragma unroll
  for (int mi = 0; mi < 8; mi++)
#pragma unroll
    for (int ni = 0; ni < 4; ni++) {
      long m = m0 + wrow + mi * 16 + qd * 4;   // C/D: row=(lane>>4)*4+reg
      long n = n0 + wcol + ni * 16 + lm;       //      col=lane&15
      u16* ptr = xw + m * D_ + n;
#pragma unroll
      for (int r = 0; r < 4; r++) ptr[(long)r * D_] = f2h(acc[mi][ni][r]);
    }
}

// ---------------- K2: eij 256x256 tile + fused tanh*cv reduction -> partial scores ----
// 256 blocks (1/CU). 4 blocks per batch share xw/xh panels in XCD-L2.
// 8 planes: plane = st*4 + (wave&3); each plane covers a disjoint 64-wide s-range.
__global__ __launch_bounds__(512, 2) void gemm2_kernel(const u16* __restrict__ xw,
                                                       const u16* __restrict__ xh,
                                                       const float* __restrict__ bias,
                                                       const float* __restrict__ cv,
                                                       float* __restrict__ scores_part) {
  __shared__ u16 As[4 * 8192];
  __shared__ u16 Bs[4 * 8192];
  f32x4 acc[8][4] = {};
  const int tid = threadIdx.x;
  const int bx = blockIdx.x;                 // 256 blocks
  const int xcd = bx & 7, j = bx >> 3;       // j in [0,32)
  const int bb = xcd * 8 + (j >> 2);         // 64 batches, 8 per XCD
  const int tile = j & 3;
  const int tt = tile >> 1, st_ = tile & 1;  // t-half, s-half
  const long arow = (long)bb * T_ + tt * 256;
  const long brow = (long)bb * T_ + st_ * 256;
  gemm_core256(xw + arow * D_, xh + brow * D_, As, Bs, tid, acc);

  const int wave = tid >> 6, lane = tid & 63;
  const int wrow = (wave >> 2) * 128, wcol = (wave & 3) * 64;
  const int lm = lane & 15, qd = lane >> 4;
  float cvv[4], bv[4];
#pragma unroll
  for (int ni = 0; ni < 4; ni++) {
    int s = st_ * 256 + wcol + ni * 16 + lm;
    cvv[ni] = cv[s];
    bv[ni] = bias[s];
  }
  const int plane = st_ * 4 + (wave & 3);
  float* dst = scores_part + plane * (B_ * T_) + bb * T_ + tt * 256;
#pragma unroll
  for (int mi = 0; mi < 8; mi++) {
#pragma unroll
    for (int r = 0; r < 4; r++) {
      float p = 0.f;
#pragma unroll
      for (int ni = 0; ni < 4; ni++) p += fast_tanh(acc[mi][ni][r] + bv[ni]) * cvv[ni];
      p += __shfl_xor(p, 1); p += __shfl_xor(p, 2);
      p += __shfl_xor(p, 4); p += __shfl_xor(p, 8);
      if (lm == 0) dst[wrow + mi * 16 + qd * 4 + r] = p;   // unique (plane,b,t) owner
    }
  }
}

// ---------------- K3: fused masked-softmax + weighted-sum ----------------
// grid (64,4) x 256 thr. Each block: softmax of batch b (redundant x4, cheap),
// a_out written by dq==0 blocks only; then wsum of its 256-d slice (atomic-free).
__global__ __launch_bounds__(256) void sm_wsum_kernel(const float* __restrict__ sp,
                                                      const unsigned char* __restrict__ m8,
                                                      const u16* __restrict__ xh,
                                                      float* __restrict__ a_out,
                                                      float* __restrict__ out) {
  __shared__ float a_sh[512];
  __shared__ float red[8];
  __shared__ int nonz;
  __shared__ float4 lred[4][64];
  const int b = blockIdx.x, dq = blockIdx.y, tid = threadIdx.x;
  const int w = tid >> 6, ln = tid & 63;
  if (tid == 0) nonz = 0;
  __syncthreads();
  // detect int32-vs-uint8 bool storage from first 512 mask words
  {
    unsigned char c = m8[tid * 4 + 1] | m8[tid * 4 + 2] | m8[tid * 4 + 3] |
                      m8[(tid + 256) * 4 + 1] | m8[(tid + 256) * 4 + 2] | m8[(tid + 256) * 4 + 3];
    if (c) atomicOr(&nonz, 1);
  }
  __syncthreads();
  const bool is_i32 = (nonz == 0);
  float v[2]; bool valid[2];
#pragma unroll
  for (int h = 0; h < 2; h++) {
    int t = tid + h * 256;
    int idx = b * T_ + t;
    valid[h] = is_i32 ? (m8[(long)idx * 4] != 0) : (m8[idx] != 0);
    float s = 0.f;
#pragma unroll
    for (int pl = 0; pl < 8; pl++) s += sp[pl * (B_ * T_) + idx];
    v[h] = valid[h] ? s : -INFINITY;
  }
  float m = fmaxf(v[0], v[1]);
#pragma unroll
  for (int o = 32; o > 0; o >>= 1) m = fmaxf(m, __shfl_xor(m, o));
  if (ln == 0) red[w] = m;
  __syncthreads();
  const float rowmax = fmaxf(fmaxf(red[0], red[1]), fmaxf(red[2], red[3]));
  float e0 = valid[0] ? expf(v[0] - rowmax) : 0.f;
  float e1 = valid[1] ? expf(v[1] - rowmax) : 0.f;
  float ss = e0 + e1;
#pragma unroll
  for (int o = 32; o > 0; o >>= 1) ss += __shfl_xor(ss, o);
  if (ln == 0) red[4 + w] = ss;
  __syncthreads();
  const float tot = red[4] + red[5] + red[6] + red[7];
  const float a0 = e0 / tot, a1 = e1 / tot;
  a_sh[tid] = a0; a_sh[tid + 256] = a1;
  if (dq == 0) {
    a_out[b * T_ + tid] = a0;
    a_out[b * T_ + tid + 256] = a1;
  }
  __syncthreads();
  // weighted sum: lane covers 4 d's; wave w sums t in [w*128,(w+1)*128)
  const int d0 = dq * 256 + ln * 4;
  const u16* xp = xh + (long)b * T_ * D_ + d0;
  float4 acc = make_float4(0.f, 0.f, 0.f, 0.f);
  for (int i = 0; i < 128; i++) {
    int t = w * 128 + i;
    float av = a_sh[t];
    ushort4 xv = *(const ushort4*)(xp + (long)t * D_);
    acc.x += av * h2f(xv.x); acc.y += av * h2f(xv.y);
    acc.z += av * h2f(xv.z); acc.w += av * h2f(xv.w);
  }
  lred[w][ln] = acc;
  __syncthreads();
  if (w == 0) {
    float4 s0 = lred[0][ln], s1 = lred[1][ln], s2 = lred[2][ln], s3 = lred[3][ln];
    float4 s;
    s.x = s0.x + s1.x + s2.x + s3.x;
    s.y = s0.y + s1.y + s2.y + s3.y;
    s.z = s0.z + s1.z + s2.z + s3.z;
    s.w = s0.w + s1.w + s2.w + s3.w;
    *(float4*)(out + (long)b * D_ + d0) = s;
  }
}

extern "C" void kernel_launch(void* const* d_in, const int* in_sizes, int n_in,
                              void* d_out, int out_size, void* d_ws, size_t ws_size,
                              hipStream_t stream) {
  const float* x = (const float*)d_in[0];
  const unsigned char* mask = (const unsigned char*)d_in[1];
  const float* W = (const float*)d_in[2];
  const float* cv = (const float*)d_in[3];
  const float* bias = (const float*)d_in[4];

  float* out = (float*)d_out;                  // [B,D]
  float* a_out = out + (size_t)B_ * D_;        // [B,T]

  // workspace layout (130 MiB): scores_part (1 MiB, 8 planes) aliases wt (dead after gemm1)
  char* ws = (char*)d_ws;
  u16* xh = (u16*)(ws);                         // fp16 x    [M_, D_]  64 MiB
  u16* wt = (u16*)(ws + 67108864);              // fp16 W^T  [D_, D_]   2 MiB
  float* scores_part = (float*)(ws + 67108864); // fp32 [8][B_,T_] 1 MiB (aliases wt)
  u16* xw = (u16*)(ws + 69206016);              // fp16 x@W  [M_, D_]  64 MiB

  cvt_kernel<<<32768 + 1024, 256, 0, stream>>>((const float4*)x, (ushort4*)xh, W, wt);
  gemm1_kernel<<<512, 512, 0, stream>>>(xh, wt, xw);
  gemm2_kernel<<<256, 512, 0, stream>>>(xw, xh, bias, cv, scores_part);
  sm_wsum_kernel<<<dim3(B_, 4), 256, 0, stream>>>(scores_part, mask, xh, a_out, out);
}

// Round 3
// 318.230 us; speedup vs baseline: 1.0753x; 1.0284x over previous
//
#include <hip/hip_runtime.h>
#include <hip/hip_bf16.h>
#include <math.h>

#define B_ 64
#define T_ 512
#define D_ 1024
#define M_ (B_*T_)   // 32768 rows of x flattened [B*T, D]

typedef unsigned short u16;
typedef __attribute__((ext_vector_type(8))) _Float16 f16x8;  // 8 fp16 in 4 VGPRs
typedef __attribute__((ext_vector_type(4))) float f32x4;

// fp32 -> fp16 RNE, bit pattern
__device__ __forceinline__ u16 f2h(float f) {
  union { _Float16 h; u16 u; } v;
  v.h = (_Float16)f;
  return v.u;
}

__device__ __forceinline__ float h2f(u16 u) {
  union { u16 u; _Float16 h; } v;
  v.u = u;
  return (float)v.h;
}

__device__ __forceinline__ float fast_tanh(float x) {
  // tanh(x) = 1 - 2/(exp(2x)+1); saturates correctly at +/-inf of expf
  return 1.0f - 2.0f / (__expf(2.0f * x) + 1.0f);
}

// async global->LDS, 16B per lane; LDS dest = wave-uniform base + lane*16
__device__ __forceinline__ void gll16(const void* g, void* l) {
  __builtin_amdgcn_global_load_lds(
      (const __attribute__((address_space(1))) unsigned int*)g,
      (__attribute__((address_space(3))) unsigned int*)l, 16, 0, 0);
}

// ---------------- K0: fused cvt — blocks <32768: x fp32->fp16; rest: W -> Wt ------
__global__ __launch_bounds__(256) void cvt_kernel(const float4* __restrict__ x,
                                                  ushort4* __restrict__ xh,
                                                  const float* __restrict__ W,
                                                  u16* __restrict__ wt) {
  __shared__ float tile[32][33];
  const int bid = blockIdx.x;
  if (bid < 32768) {
    int i = bid * 256 + threadIdx.x;
    float4 v = x[i];
    ushort4 o;
    o.x = f2h(v.x); o.y = f2h(v.y); o.z = f2h(v.z); o.w = f2h(v.w);
    xh[i] = o;
  } else {
    const int tb = bid - 32768;                 // 1024 transpose tiles
    const int n0 = (tb & 31) * 32, k0 = (tb >> 5) * 32;
    const int tx = threadIdx.x & 31, ty = threadIdx.x >> 5;  // ty 0..7
#pragma unroll
    for (int ph = 0; ph < 4; ph++)
      tile[ty + ph * 8][tx] = W[(k0 + ty + ph * 8) * D_ + n0 + tx];
    __syncthreads();
#pragma unroll
    for (int ph = 0; ph < 4; ph++)
      wt[(long)(n0 + ty + ph * 8) * D_ + k0 + tx] = f2h(tile[tx][ty + ph * 8]);
  }
}

// ---------------- shared core: 256x128 tile, BK=64, 4 waves (round-0 verified) -------
// BK=64 swizzle: row r (64 elems = 8 chunks of 16B), logical chunk c stored at
// position (c + (r>>1)) & 7. Staging lane (p=lane&7, rl=lane>>3) of group g
// (rows g*8..g*8+7) fetches global chunk (p - (r>>1)) & 7. Per-16-lane phase the
// read hits 8 distinct 4-bank groups, 2 lanes each -> conflict-free (measured 0).
__device__ __forceinline__ void gemm_core256x128(const u16* __restrict__ Abase,
                                                 const u16* __restrict__ Bbase,
                                                 u16* As, u16* Bs, int tid,
                                                 f32x4 (&acc)[8][4]) {
  const int wave = tid >> 6, lane = tid & 63;
  const int p = lane & 7, rl = lane >> 3;    // staging coords within 8-row group

  const u16* gA[8]; u16* lA[8];
#pragma unroll
  for (int i = 0; i < 8; i++) {              // A: 32 groups, 8 per wave
    int g = wave * 8 + i;
    int r = g * 8 + rl;
    int c = (p - (r >> 1)) & 7;
    gA[i] = Abase + (long)r * D_ + c * 8;
    lA[i] = As + g * 512;
  }
  const u16* gB[4]; u16* lB[4];
#pragma unroll
  for (int i = 0; i < 4; i++) {              // B: 16 groups, 4 per wave
    int g = wave * 4 + i;
    int r = g * 8 + rl;
    int c = (p - (r >> 1)) & 7;
    gB[i] = Bbase + (long)r * D_ + c * 8;
    lB[i] = Bs + g * 512;
  }

  const int wrow = (wave >> 1) * 128, wcol = (wave & 1) * 64;
  const int lm = lane & 15, qd = lane >> 4;
  const u16* ra = As + (wrow + lm) * 64;
  const u16* rb = Bs + (wcol + lm) * 64;
  // read-side chunk position: p' = (kk*4 + qd + (m>>1)) & 7; m-tile terms vanish mod 8
  const int pk0 = ((qd + (lm >> 1)) & 7) * 8;
  const int pk1 = ((qd + 4 + (lm >> 1)) & 7) * 8;

  for (int kt = 0; kt < D_; kt += 64) {
#pragma unroll
    for (int i = 0; i < 8; i++) { gll16(gA[i], lA[i]); gA[i] += 64; }
#pragma unroll
    for (int i = 0; i < 4; i++) { gll16(gB[i], lB[i]); gB[i] += 64; }
    __syncthreads();
#pragma unroll
    for (int kk = 0; kk < 2; kk++) {
      const int pk = kk ? pk1 : pk0;
      f16x8 af[8], bfr[4];
#pragma unroll
      for (int i = 0; i < 8; i++) af[i] = *(const f16x8*)(ra + i * 16 * 64 + pk);
#pragma unroll
      for (int i = 0; i < 4; i++) bfr[i] = *(const f16x8*)(rb + i * 16 * 64 + pk);
#pragma unroll
      for (int mi = 0; mi < 8; mi++)
#pragma unroll
        for (int ni = 0; ni < 4; ni++)
          acc[mi][ni] = __builtin_amdgcn_mfma_f32_16x16x32_f16(af[mi], bfr[ni], acc[mi][ni], 0, 0, 0);
    }
    __syncthreads();
  }
}

// ---------------- K1: xw = x @ W  — 256x128 tile, BK=64, 1024 blocks (round-0) -------
__global__ __launch_bounds__(256, 2) void gemm1_kernel(const u16* __restrict__ xh,
                                                       const u16* __restrict__ wt,
                                                       u16* __restrict__ xw) {
  __shared__ u16 As[256 * 64];   // 32 KB
  __shared__ u16 Bs[128 * 64];   // 16 KB
  f32x4 acc[8][4] = {};
  const int tid = threadIdx.x;
  const int bx = blockIdx.x;                 // 1024 blocks
  const int xcd = bx & 7, j = bx >> 3;       // j in [0,128)
  const int mt = xcd * 16 + (j >> 3);        // 128 m-tiles of 256 rows
  const int nt = j & 7;                      // 8 n-tiles of 128
  const long m0 = (long)mt * 256;
  const long n0 = (long)nt * 128;
  gemm_core256x128(xh + m0 * D_, wt + n0 * D_, As, Bs, tid, acc);

  const int wave = tid >> 6, lane = tid & 63;
  const int wrow = (wave >> 1) * 128, wcol = (wave & 1) * 64;
  const int lm2 = lane & 15, qd2 = lane >> 4;
#pragma unroll
  for (int mi = 0; mi < 8; mi++)
#pragma unroll
    for (int ni = 0; ni < 4; ni++) {
      long m = m0 + wrow + mi * 16 + qd2 * 4;  // C/D: row=(lane>>4)*4+reg
      long n = n0 + wcol + ni * 16 + lm2;      //      col=lane&15
      u16* ptr = xw + m * D_ + n;
#pragma unroll
      for (int r = 0; r < 4; r++) ptr[(long)r * D_] = f2h(acc[mi][ni][r]);
    }
}

// ---------------- K2: eij on the SAME 256x128/BK=64 core + fused tanh*cv epilogue ----
// 512 blocks (2/CU, all co-resident). Per batch: 2 m-tiles (256 t-rows) x 4 n-tiles
// (128 s-cols) = 8 blocks; same-batch blocks share one XCD (2 MB working set in L2).
// 8 planes: plane = nt*2 + (wave&1); each plane is a disjoint 64-wide s-slice and
// fully tiles [B,T] via (mt, wrow, mi, qd, r) -> race-free.
__global__ __launch_bounds__(256, 2) void gemm2_kernel(const u16* __restrict__ xw,
                                                       const u16* __restrict__ xh,
                                                       const float* __restrict__ bias,
                                                       const float* __restrict__ cv,
                                                       float* __restrict__ scores_part) {
  __shared__ u16 As[256 * 64];   // 32 KB
  __shared__ u16 Bs[128 * 64];   // 16 KB
  f32x4 acc[8][4] = {};
  const int tid = threadIdx.x;
  const int bx = blockIdx.x;                 // 512 blocks
  const int xcd = bx & 7, j = bx >> 3;       // j in [0,64)
  const int bb = xcd * 8 + (j >> 3);         // 64 batches, 8 per XCD
  const int tile = j & 7;                    // 8 tiles per batch
  const int mt = tile >> 2, nt = tile & 3;   // mt: 2 x 256 t-rows; nt: 4 x 128 s-cols
  const u16* Abase = xw + ((long)bb * T_ + mt * 256) * D_;
  const u16* Bbase = xh + ((long)bb * T_ + nt * 128) * D_;
  gemm_core256x128(Abase, Bbase, As, Bs, tid, acc);

  const int wave = tid >> 6, lane = tid & 63;
  const int wrow = (wave >> 1) * 128, wcol = (wave & 1) * 64;
  const int lm2 = lane & 15, qd2 = lane >> 4;
  float cvv[4], bv[4];
#pragma unroll
  for (int ni = 0; ni < 4; ni++) {
    int s = nt * 128 + wcol + ni * 16 + lm2;
    cvv[ni] = cv[s];
    bv[ni] = bias[s];
  }
  const int plane = nt * 2 + (wave & 1);
  float* dst = scores_part + plane * (B_ * T_) + bb * T_ + mt * 256;
#pragma unroll
  for (int mi = 0; mi < 8; mi++) {
#pragma unroll
    for (int r = 0; r < 4; r++) {
      float p = 0.f;
#pragma unroll
      for (int ni = 0; ni < 4; ni++) p += fast_tanh(acc[mi][ni][r] + bv[ni]) * cvv[ni];
      p += __shfl_xor(p, 1); p += __shfl_xor(p, 2);
      p += __shfl_xor(p, 4); p += __shfl_xor(p, 8);
      if (lm2 == 0) dst[wrow + mi * 16 + qd2 * 4 + r] = p;  // unique (plane,b,t) owner
    }
  }
}

// ---------------- K3: fused masked-softmax + weighted-sum ----------------
// grid (64,4) x 256 thr. Each block: softmax of batch b (redundant x4, cheap),
// a_out written by dq==0 blocks only; then wsum of its 256-d slice (atomic-free).
__global__ __launch_bounds__(256) void sm_wsum_kernel(const float* __restrict__ sp,
                                                      const unsigned char* __restrict__ m8,
                                                      const u16* __restrict__ xh,
                                                      float* __restrict__ a_out,
                                                      float* __restrict__ out) {
  __shared__ float a_sh[512];
  __shared__ float red[8];
  __shared__ int nonz;
  __shared__ float4 lred[4][64];
  const int b = blockIdx.x, dq = blockIdx.y, tid = threadIdx.x;
  const int w = tid >> 6, ln = tid & 63;
  if (tid == 0) nonz = 0;
  __syncthreads();
  // detect int32-vs-uint8 bool storage from first 512 mask words
  {
    unsigned char c = m8[tid * 4 + 1] | m8[tid * 4 + 2] | m8[tid * 4 + 3] |
                      m8[(tid + 256) * 4 + 1] | m8[(tid + 256) * 4 + 2] | m8[(tid + 256) * 4 + 3];
    if (c) atomicOr(&nonz, 1);
  }
  __syncthreads();
  const bool is_i32 = (nonz == 0);
  float v[2]; bool valid[2];
#pragma unroll
  for (int h = 0; h < 2; h++) {
    int t = tid + h * 256;
    int idx = b * T_ + t;
    valid[h] = is_i32 ? (m8[(long)idx * 4] != 0) : (m8[idx] != 0);
    float s = 0.f;
#pragma unroll
    for (int pl = 0; pl < 8; pl++) s += sp[pl * (B_ * T_) + idx];
    v[h] = valid[h] ? s : -INFINITY;
  }
  float m = fmaxf(v[0], v[1]);
#pragma unroll
  for (int o = 32; o > 0; o >>= 1) m = fmaxf(m, __shfl_xor(m, o));
  if (ln == 0) red[w] = m;
  __syncthreads();
  const float rowmax = fmaxf(fmaxf(red[0], red[1]), fmaxf(red[2], red[3]));
  float e0 = valid[0] ? expf(v[0] - rowmax) : 0.f;
  float e1 = valid[1] ? expf(v[1] - rowmax) : 0.f;
  float ss = e0 + e1;
#pragma unroll
  for (int o = 32; o > 0; o >>= 1) ss += __shfl_xor(ss, o);
  if (ln == 0) red[4 + w] = ss;
  __syncthreads();
  const float tot = red[4] + red[5] + red[6] + red[7];
  const float a0 = e0 / tot, a1 = e1 / tot;
  a_sh[tid] = a0; a_sh[tid + 256] = a1;
  if (dq == 0) {
    a_out[b * T_ + tid] = a0;
    a_out[b * T_ + tid + 256] = a1;
  }
  __syncthreads();
  // weighted sum: lane covers 4 d's; wave w sums t in [w*128,(w+1)*128)
  const int d0 = dq * 256 + ln * 4;
  const u16* xp = xh + (long)b * T_ * D_ + d0;
  float4 acc = make_float4(0.f, 0.f, 0.f, 0.f);
  for (int i = 0; i < 128; i++) {
    int t = w * 128 + i;
    float av = a_sh[t];
    ushort4 xv = *(const ushort4*)(xp + (long)t * D_);
    acc.x += av * h2f(xv.x); acc.y += av * h2f(xv.y);
    acc.z += av * h2f(xv.z); acc.w += av * h2f(xv.w);
  }
  lred[w][ln] = acc;
  __syncthreads();
  if (w == 0) {
    float4 s0 = lred[0][ln], s1 = lred[1][ln], s2 = lred[2][ln], s3 = lred[3][ln];
    float4 s;
    s.x = s0.x + s1.x + s2.x + s3.x;
    s.y = s0.y + s1.y + s2.y + s3.y;
    s.z = s0.z + s1.z + s2.z + s3.z;
    s.w = s0.w + s1.w + s2.w + s3.w;
    *(float4*)(out + (long)b * D_ + d0) = s;
  }
}

extern "C" void kernel_launch(void* const* d_in, const int* in_sizes, int n_in,
                              void* d_out, int out_size, void* d_ws, size_t ws_size,
                              hipStream_t stream) {
  const float* x = (const float*)d_in[0];
  const unsigned char* mask = (const unsigned char*)d_in[1];
  const float* W = (const float*)d_in[2];
  const float* cv = (const float*)d_in[3];
  const float* bias = (const float*)d_in[4];

  float* out = (float*)d_out;                  // [B,D]
  float* a_out = out + (size_t)B_ * D_;        // [B,T]

  // workspace layout (130 MiB): scores_part (1 MiB, 8 planes) aliases wt (dead after gemm1)
  char* ws = (char*)d_ws;
  u16* xh = (u16*)(ws);                         // fp16 x    [M_, D_]  64 MiB
  u16* wt = (u16*)(ws + 67108864);              // fp16 W^T  [D_, D_]   2 MiB
  float* scores_part = (float*)(ws + 67108864); // fp32 [8][B_,T_] 1 MiB (aliases wt)
  u16* xw = (u16*)(ws + 69206016);              // fp16 x@W  [M_, D_]  64 MiB

  cvt_kernel<<<32768 + 1024, 256, 0, stream>>>((const float4*)x, (ushort4*)xh, W, wt);
  gemm1_kernel<<<1024, 256, 0, stream>>>(xh, wt, xw);
  gemm2_kernel<<<512, 256, 0, stream>>>(xw, xh, bias, cv, scores_part);
  sm_wsum_kernel<<<dim3(B_, 4), 256, 0, stream>>>(scores_part, mask, xh, a_out, out);
}